// Round 6
// baseline (930.910 us; speedup 1.0000x reference)
//
#include <hip/hip_runtime.h>
#include <hip/hip_fp16.h>

// N=100000 nodes, 64 in-feats, 32 hidden, E=3200000 edges per type.
// R5 structure (pk_f16 push-scatter, 102.4M atomics) with grid-stride
// persistent workgroups everywhere. R1/R5 both ran the scatter at exactly
// 0.5 WG/cycle (800K WG/662us, 400K WG/330us) -- this round distinguishes
// WG-dispatch-rate-bound from atomic-op-rate-bound by cutting total WGs
// 444K -> ~10K with zero change to op counts or bytes.

__global__ __launch_bounds__(256, 8)
void count_kernel(const int* __restrict__ ei_n, const int* __restrict__ ei_s,
                  int* __restrict__ cnt, int N, int En, int Es) {
    int stride = gridDim.x * blockDim.x;
    int Etot = En + Es;
    for (int i = blockIdx.x * blockDim.x + threadIdx.x; i < Etot; i += stride) {
        if (i < En) {
            int d = __builtin_nontemporal_load(&ei_n[En + i]);
            atomicAdd(&cnt[d], 1);
        } else {
            int e = i - En;
            int d = __builtin_nontemporal_load(&ei_s[Es + e]);
            atomicAdd(&cnt[N + d], 1);
        }
    }
}

// xws[type][node] = (x[node] @ W_type) * rsqrt(cnt+1), packed __half2
// (feats 2sl,2sl+1 in word sl). acc seeded with same value (self-loop msg).
__global__ __launch_bounds__(256, 8)
void xw_kernel(const float* __restrict__ x,
               const float* __restrict__ Wn, const float* __restrict__ Ws,
               const int* __restrict__ cnt,
               __half2* __restrict__ xws, __half2* __restrict__ acc, int N) {
    __shared__ float wn[64 * 32];
    __shared__ float wsm[64 * 32];
    for (int i = threadIdx.x; i < 64 * 32; i += blockDim.x) {
        wn[i] = Wn[i];
        wsm[i] = Ws[i];
    }
    __syncthreads();
    int lane = threadIdx.x & 31;
    int wid = threadIdx.x >> 5;                  // 8 node-groups per block
    int gstride = gridDim.x * 8;
    for (int node = blockIdx.x * 8 + wid; node < N; node += gstride) {
        const float4* x4 = (const float4*)(x + (size_t)node * 64);
        float an = 0.f, as = 0.f;
#pragma unroll
        for (int k4 = 0; k4 < 16; ++k4) {
            float4 xv = x4[k4];
            int k = k4 * 4;
            an += xv.x * wn[(k + 0) * 32 + lane] + xv.y * wn[(k + 1) * 32 + lane]
                + xv.z * wn[(k + 2) * 32 + lane] + xv.w * wn[(k + 3) * 32 + lane];
            as += xv.x * wsm[(k + 0) * 32 + lane] + xv.y * wsm[(k + 1) * 32 + lane]
                + xv.z * wsm[(k + 2) * 32 + lane] + xv.w * wsm[(k + 3) * 32 + lane];
        }
        float vn = an * rsqrtf((float)cnt[node] + 1.0f);
        float vs = as * rsqrtf((float)cnt[N + node] + 1.0f);
        int sl = lane & 15;
        float vn0 = __shfl(vn, 2 * sl, 32);
        float vn1 = __shfl(vn, 2 * sl + 1, 32);
        float vs0 = __shfl(vs, 2 * sl, 32);
        float vs1 = __shfl(vs, 2 * sl + 1, 32);
        if (lane < 16) {
            __half2 hn = __floats2half2_rn(vn0, vn1);
            __half2 hs = __floats2half2_rn(vs0, vs1);
            size_t on = (size_t)node * 16 + sl;
            size_t os = ((size_t)N + node) * 16 + sl;
            xws[on] = hn;
            acc[on] = hn;
            xws[os] = hs;
            acc[os] = hs;
        }
    }
}

// Grid-stride push-scatter: 16 lanes per edge, pk_add_f16 into acc[dst].
__global__ __launch_bounds__(256, 8)
void scatter_kernel(const int* __restrict__ ei_n, const int* __restrict__ ei_s,
                    const __half2* __restrict__ xws, __half2* __restrict__ acc,
                    int N, int En, int Es) {
    int sl = threadIdx.x & 15;
    int g = (blockIdx.x * blockDim.x + threadIdx.x) >> 4;
    int ngroups = (gridDim.x * blockDim.x) >> 4;
    int Etot = En + Es;
    for (int e = g; e < Etot; e += ngroups) {
        int src, dst;
        size_t base;
        if (e < En) {
            src = __builtin_nontemporal_load(&ei_n[e]);
            dst = __builtin_nontemporal_load(&ei_n[En + e]);
            base = 0;
        } else {
            int e2 = e - En;
            src = __builtin_nontemporal_load(&ei_s[e2]);
            dst = __builtin_nontemporal_load(&ei_s[Es + e2]);
            base = (size_t)N;
        }
        __half2 w = xws[(base + src) * 16 + sl];
        unsafeAtomicAdd(&acc[(base + dst) * 16 + sl], w);   // global_atomic_pk_add_f16
    }
}

// out[d] = dot(relu(acc_n*dinv_n + b_n + acc_s*dinv_s + b_s), W_lin) + b_lin
__global__ __launch_bounds__(256, 8)
void epilogue_kernel(const __half2* __restrict__ acc, const int* __restrict__ cnt,
                     const float* __restrict__ b_n, const float* __restrict__ b_s,
                     const float* __restrict__ W_lin, const float* __restrict__ b_lin,
                     float* __restrict__ out, int N) {
    int sl = threadIdx.x & 15;
    int g = (blockIdx.x * blockDim.x + threadIdx.x) >> 4;
    int gs = (gridDim.x * blockDim.x) >> 4;
    float bn0 = b_n[2 * sl], bn1 = b_n[2 * sl + 1];
    float bs0 = b_s[2 * sl], bs1 = b_s[2 * sl + 1];
    float wl0 = W_lin[2 * sl], wl1 = W_lin[2 * sl + 1];
    float bl = b_lin[0];
    for (int node = g; node < N; node += gs) {
        float2 an = __half22float2(acc[(size_t)node * 16 + sl]);
        float2 as = __half22float2(acc[((size_t)N + node) * 16 + sl]);
        float dn = rsqrtf((float)cnt[node] + 1.0f);
        float dsv = rsqrtf((float)cnt[N + node] + 1.0f);
        float h0 = an.x * dn + bn0 + as.x * dsv + bs0;
        float h1 = an.y * dn + bn1 + as.y * dsv + bs1;
        float p = fmaxf(h0, 0.f) * wl0 + fmaxf(h1, 0.f) * wl1;
#pragma unroll
        for (int off = 8; off > 0; off >>= 1) p += __shfl_xor(p, off, 16);
        if (sl == 0) out[node] = p + bl;
    }
}

extern "C" void kernel_launch(void* const* d_in, const int* in_sizes, int n_in,
                              void* d_out, int out_size, void* d_ws, size_t ws_size,
                              hipStream_t stream) {
    const float* x     = (const float*)d_in[0];
    const int*   ei_n  = (const int*)d_in[1];
    const int*   ei_s  = (const int*)d_in[2];
    const float* W_n   = (const float*)d_in[3];
    const float* b_n   = (const float*)d_in[4];
    const float* W_s   = (const float*)d_in[5];
    const float* b_s   = (const float*)d_in[6];
    const float* W_lin = (const float*)d_in[7];
    const float* b_lin = (const float*)d_in[8];
    float* out = (float*)d_out;

    const int N    = in_sizes[0] / 64;   // 100000
    const int En   = in_sizes[1] / 2;    // 3200000
    const int Es   = in_sizes[2] / 2;    // 3200000
    const int M    = 2 * N;

    // Workspace (4B words), ~26.4 MB: cnt[2N] | xws[2N*16 half2] | acc[2N*16 half2]
    int*     cnt = (int*)d_ws;
    __half2* xws = (__half2*)(cnt + (size_t)M);
    __half2* acc = xws + (size_t)16 * M;

    hipMemsetAsync(cnt, 0, (size_t)M * sizeof(int), stream);

    count_kernel<<<2048, 256, 0, stream>>>(ei_n, ei_s, cnt, N, En, Es);
    xw_kernel<<<2048, 256, 0, stream>>>(x, W_n, W_s, cnt, xws, acc, N);
    scatter_kernel<<<4096, 256, 0, stream>>>(ei_n, ei_s, xws, acc, N, En, Es);
    epilogue_kernel<<<2048, 256, 0, stream>>>(acc, cnt, b_n, b_s, W_lin, b_lin, out, N);
}

// Round 7
// 731.287 us; speedup vs baseline: 1.2730x; 1.2730x over previous
//
#include <hip/hip_runtime.h>
#include <hip/hip_fp16.h>

// N=100000 nodes, 64 in-feats, 32 hidden, E=3200000 edges per type.
// R5 structure (pk_f16 push-scatter at the ~310 G atomic-op/s fabric ceiling,
// proven 330us twice) + 8-way striped degree counters to break the ~32-way
// same-address contention in count_kernel (est. ~250us of R5's 397us
// remainder). R6 lesson: grid-stride persistent forms REGRESSED the small
// kernels by 205us -- one-shot forms restored.

__global__ void count_kernel(const int* __restrict__ ei_n, const int* __restrict__ ei_s,
                             int* __restrict__ cnt8, int N, int En, int Es) {
    int gid = blockIdx.x * blockDim.x + threadIdx.x;
    int stripe = threadIdx.x & 7;
    int M = 2 * N;
    if (gid < En) {
        atomicAdd(&cnt8[stripe * M + ei_n[En + gid]], 1);
    } else if (gid < En + Es) {
        int e = gid - En;
        atomicAdd(&cnt8[stripe * M + N + ei_s[Es + e]], 1);
    }
}

// Fold 8 stripes -> dinv = rsqrt(deg + 1)
__global__ void dinv_kernel(const int* __restrict__ cnt8, float* __restrict__ dinv, int M) {
    int i = blockIdx.x * blockDim.x + threadIdx.x;
    if (i >= M) return;
    int s = 0;
#pragma unroll
    for (int k = 0; k < 8; ++k) s += cnt8[k * M + i];
    dinv[i] = rsqrtf((float)s + 1.0f);   // +1 = self-loop
}

// xws[type][node] = (x[node] @ W_type) * dinv[type][node], packed __half2
// (feats 2sl, 2sl+1 in word sl). acc seeded with same value (self-loop msg).
__global__ void xw_kernel(const float* __restrict__ x,
                          const float* __restrict__ Wn, const float* __restrict__ Ws,
                          const float* __restrict__ dinv,
                          __half2* __restrict__ xws, __half2* __restrict__ acc, int N) {
    __shared__ float wn[64 * 32];
    __shared__ float wsm[64 * 32];
    for (int i = threadIdx.x; i < 64 * 32; i += blockDim.x) {
        wn[i] = Wn[i];
        wsm[i] = Ws[i];
    }
    __syncthreads();
    int lane = threadIdx.x & 31;
    int node = blockIdx.x * (blockDim.x >> 5) + (threadIdx.x >> 5);
    if (node >= N) return;

    const float4* x4 = (const float4*)(x + (size_t)node * 64);
    float an = 0.f, as = 0.f;
#pragma unroll
    for (int k4 = 0; k4 < 16; ++k4) {
        float4 xv = x4[k4];
        int k = k4 * 4;
        an += xv.x * wn[(k + 0) * 32 + lane] + xv.y * wn[(k + 1) * 32 + lane]
            + xv.z * wn[(k + 2) * 32 + lane] + xv.w * wn[(k + 3) * 32 + lane];
        as += xv.x * wsm[(k + 0) * 32 + lane] + xv.y * wsm[(k + 1) * 32 + lane]
            + xv.z * wsm[(k + 2) * 32 + lane] + xv.w * wsm[(k + 3) * 32 + lane];
    }
    float vn = an * dinv[node];
    float vs = as * dinv[N + node];
    int sl = lane & 15;
    float vn0 = __shfl(vn, 2 * sl, 32);
    float vn1 = __shfl(vn, 2 * sl + 1, 32);
    float vs0 = __shfl(vs, 2 * sl, 32);
    float vs1 = __shfl(vs, 2 * sl + 1, 32);
    if (lane < 16) {
        __half2 hn = __floats2half2_rn(vn0, vn1);
        __half2 hs = __floats2half2_rn(vs0, vs1);
        size_t on = (size_t)node * 16 + sl;
        size_t os = ((size_t)N + node) * 16 + sl;
        xws[on] = hn;
        acc[on] = hn;
        xws[os] = hs;
        acc[os] = hs;
    }
}

// Per edge: 16 lanes gather packed msg row (64B) and pk_add_f16 into acc[dst].
__global__ void scatter_kernel(const int* __restrict__ ei_n, const int* __restrict__ ei_s,
                               const __half2* __restrict__ xws, __half2* __restrict__ acc,
                               int N, int En, int Es) {
    unsigned int gid = blockIdx.x * blockDim.x + threadIdx.x;
    unsigned int e = gid >> 4;
    int sl = gid & 15;
    int src, dst;
    size_t base;
    if (e < (unsigned)En) {
        src = ei_n[e]; dst = ei_n[En + e]; base = 0;
    } else if (e < (unsigned)(En + Es)) {
        unsigned e2 = e - En;
        src = ei_s[e2]; dst = ei_s[Es + e2]; base = (size_t)N;
    } else {
        return;
    }
    __half2 w = xws[(base + src) * 16 + sl];
    unsafeAtomicAdd(&acc[(base + dst) * 16 + sl], w);   // global_atomic_pk_add_f16
}

// out[d] = dot(relu(acc_n*dinv_n + b_n + acc_s*dinv_s + b_s), W_lin) + b_lin
__global__ void epilogue_kernel(const __half2* __restrict__ acc,
                                const float* __restrict__ dinv,
                                const float* __restrict__ b_n, const float* __restrict__ b_s,
                                const float* __restrict__ W_lin, const float* __restrict__ b_lin,
                                float* __restrict__ out, int N) {
    int gid = blockIdx.x * blockDim.x + threadIdx.x;
    int node = gid >> 4, sl = gid & 15;
    if (node >= N) return;
    float2 an = __half22float2(acc[(size_t)node * 16 + sl]);
    float2 as = __half22float2(acc[((size_t)N + node) * 16 + sl]);
    float dn = dinv[node], dsv = dinv[N + node];
    float h0 = an.x * dn + b_n[2 * sl] + as.x * dsv + b_s[2 * sl];
    float h1 = an.y * dn + b_n[2 * sl + 1] + as.y * dsv + b_s[2 * sl + 1];
    float p = fmaxf(h0, 0.f) * W_lin[2 * sl] + fmaxf(h1, 0.f) * W_lin[2 * sl + 1];
#pragma unroll
    for (int off = 8; off > 0; off >>= 1) p += __shfl_xor(p, off, 16);
    if (sl == 0) out[node] = p + b_lin[0];
}

extern "C" void kernel_launch(void* const* d_in, const int* in_sizes, int n_in,
                              void* d_out, int out_size, void* d_ws, size_t ws_size,
                              hipStream_t stream) {
    const float* x     = (const float*)d_in[0];
    const int*   ei_n  = (const int*)d_in[1];
    const int*   ei_s  = (const int*)d_in[2];
    const float* W_n   = (const float*)d_in[3];
    const float* b_n   = (const float*)d_in[4];
    const float* W_s   = (const float*)d_in[5];
    const float* b_s   = (const float*)d_in[6];
    const float* W_lin = (const float*)d_in[7];
    const float* b_lin = (const float*)d_in[8];
    float* out = (float*)d_out;

    const int N    = in_sizes[0] / 64;   // 100000
    const int En   = in_sizes[1] / 2;    // 3200000
    const int Es   = in_sizes[2] / 2;    // 3200000
    const int Etot = En + Es;
    const int M    = 2 * N;

    // Workspace (4B words), ~33 MB:
    // cnt8[8*2N] | dinv[2N] | xws[2N*16 half2] | acc[2N*16 half2]
    int*     cnt8 = (int*)d_ws;
    float*   dinv = (float*)(cnt8 + (size_t)8 * M);
    __half2* xws  = (__half2*)(dinv + (size_t)M);
    __half2* acc  = xws + (size_t)16 * M;

    hipMemsetAsync(cnt8, 0, (size_t)8 * M * sizeof(int), stream);

    count_kernel<<<(Etot + 255) / 256, 256, 0, stream>>>(ei_n, ei_s, cnt8, N, En, Es);
    dinv_kernel<<<(M + 255) / 256, 256, 0, stream>>>(cnt8, dinv, M);

    xw_kernel<<<(N + 7) / 8, 256, 0, stream>>>(x, W_n, W_s, dinv, xws, acc, N);

    {
        size_t total = (size_t)Etot * 16;
        int blocks = (int)((total + 255) / 256);
        scatter_kernel<<<blocks, 256, 0, stream>>>(ei_n, ei_s, xws, acc, N, En, Es);
    }

    epilogue_kernel<<<(int)(((size_t)N * 16 + 255) / 256), 256, 0, stream>>>(
        acc, dinv, b_n, b_s, W_lin, b_lin, out, N);
}